// Round 1
// baseline (444.026 us; speedup 1.0000x reference)
//
#include <hip/hip_runtime.h>
#include <math.h>

#define N_NODES 50000
#define N_EDGES 1200000
#define IN_DIM  256
#define OUT_DIM 64
#define SLOPE   0.2f

// ---------------------------------------------------------------------------
// K1: z = h @ W_fc^T  (50000x256 @ 256x64), fused s_src = z@a_src, s_dst = z@a_dst
// One wave (64 threads) per block; block handles 16 nodes; lane j owns out-dim j.
// h rows staged in LDS (coalesced); W row j held in registers per 64-wide K chunk.
// ---------------------------------------------------------------------------
__global__ __launch_bounds__(64) void k_gemm(const float* __restrict__ h,
                                             const float* __restrict__ Wfc,
                                             const float* __restrict__ Wattn,
                                             float* __restrict__ z,
                                             float* __restrict__ sS,
                                             float* __restrict__ sD) {
    __shared__ float hl[16 * IN_DIM];          // 16 KB
    const int j = threadIdx.x;                 // 0..63, output dim
    const int nodeBase = blockIdx.x * 16;      // 50000/16 = 3125 blocks exactly

    // stage 16 h rows, coalesced float4
    const float4* hsrc = (const float4*)(h + (size_t)nodeBase * IN_DIM);
    float4* hd = (float4*)hl;
    #pragma unroll
    for (int t = 0; t < 16; ++t) hd[j + t * 64] = hsrc[j + t * 64];
    __syncthreads();

    const float4* Wrow = (const float4*)(Wfc + (size_t)j * IN_DIM);
    float acc[16];
    #pragma unroll
    for (int r = 0; r < 16; ++r) acc[r] = 0.f;

    for (int kb = 0; kb < 4; ++kb) {           // K chunks of 64
        float4 w[16];
        #pragma unroll
        for (int t = 0; t < 16; ++t) w[t] = Wrow[kb * 16 + t];
        #pragma unroll
        for (int r = 0; r < 16; ++r) {
            const float* hr = hl + r * IN_DIM + kb * 64;   // wave-uniform → LDS broadcast
            float a = acc[r];
            #pragma unroll
            for (int t = 0; t < 16; ++t) {
                float4 hv = ((const float4*)hr)[t];
                a += w[t].x * hv.x; a += w[t].y * hv.y;
                a += w[t].z * hv.z; a += w[t].w * hv.w;
            }
            acc[r] = a;
        }
    }

    const float aS = Wattn[j];
    const float aD = Wattn[OUT_DIM + j];
    #pragma unroll
    for (int r = 0; r < 16; ++r) {
        const size_t node = (size_t)nodeBase + r;
        z[node * OUT_DIM + j] = acc[r];
        float ss = acc[r] * aS;
        float sd = acc[r] * aD;
        #pragma unroll
        for (int off = 32; off > 0; off >>= 1) {
            ss += __shfl_down(ss, off);
            sd += __shfl_down(sd, off);
        }
        if (j == 0) { sS[node] = ss; sD[node] = sd; }
    }
}

// ---------------------------------------------------------------------------
// K2: per-edge ex = exp(leaky_relu(s_src[src]+s_dst[dst])); denom[dst] += ex
// (segment_max skipped: scores bounded ~|9|, exp fits f32; softmax invariant)
// ---------------------------------------------------------------------------
__global__ __launch_bounds__(256) void k_edge(const float* __restrict__ sS,
                                              const float* __restrict__ sD,
                                              const int* __restrict__ src,
                                              const int* __restrict__ dst,
                                              float* __restrict__ ex,
                                              float* __restrict__ denom) {
    int e = blockIdx.x * 256 + threadIdx.x;
    if (e >= N_EDGES) return;
    int d = dst[e];
    float s = sS[src[e]] + sD[d];
    float sc = s > 0.f ? s : SLOPE * s;
    float v = __expf(sc);
    ex[e] = v;
    atomicAdd(denom + d, v);
}

// ---------------------------------------------------------------------------
// K3: one wave per edge: out[dst][j] += (ex/denom[dst]) * z[src][j]
// ---------------------------------------------------------------------------
__global__ __launch_bounds__(256) void k_agg(const float* __restrict__ z,
                                             const float* __restrict__ ex,
                                             const float* __restrict__ denom,
                                             const int* __restrict__ src,
                                             const int* __restrict__ dst,
                                             float* __restrict__ out) {
    int e = blockIdx.x * 4 + (threadIdx.x >> 6);
    int lane = threadIdx.x & 63;
    if (e >= N_EDGES) return;
    int s = src[e], d = dst[e];
    float w = ex[e] / denom[d];
    float zv = z[(size_t)s * OUT_DIM + lane];
    atomicAdd(out + (size_t)d * OUT_DIM + lane, w * zv);
}

// ---------------------------------------------------------------------------
// K4: in-place ELU on d_out
// ---------------------------------------------------------------------------
__global__ __launch_bounds__(256) void k_elu(float* __restrict__ out) {
    int i = blockIdx.x * 256 + threadIdx.x;
    if (i >= N_NODES * OUT_DIM) return;
    float x = out[i];
    out[i] = x > 0.f ? x : expm1f(x);
}

extern "C" void kernel_launch(void* const* d_in, const int* in_sizes, int n_in,
                              void* d_out, int out_size, void* d_ws, size_t ws_size,
                              hipStream_t stream) {
    const float* h     = (const float*)d_in[0];
    const float* Wfc   = (const float*)d_in[1];
    const float* Wattn = (const float*)d_in[2];
    const int*   src   = (const int*)d_in[3];
    const int*   dst   = (const int*)d_in[4];
    float* out = (float*)d_out;

    // workspace layout
    char* ws = (char*)d_ws;
    float* z     = (float*)ws;                                   // 50000*64 f32 = 12.8 MB
    float* sS    = (float*)(ws + (size_t)N_NODES * OUT_DIM * 4); // 50000
    float* sD    = sS + N_NODES;                                 // 50000
    float* denom = sD + N_NODES;                                 // 50000
    float* ex    = denom + N_NODES;                              // 1.2M = 4.8 MB

    hipMemsetAsync(d_out, 0, (size_t)N_NODES * OUT_DIM * sizeof(float), stream);
    hipMemsetAsync(denom, 0, (size_t)N_NODES * sizeof(float), stream);

    k_gemm<<<N_NODES / 16, 64, 0, stream>>>(h, Wfc, Wattn, z, sS, sD);
    k_edge<<<(N_EDGES + 255) / 256, 256, 0, stream>>>(sS, sD, src, dst, ex, denom);
    k_agg<<<N_EDGES / 4, 256, 0, stream>>>(z, ex, denom, src, dst, out);
    k_elu<<<(N_NODES * OUT_DIM + 255) / 256, 256, 0, stream>>>(out);
}

// Round 2
// 347.384 us; speedup vs baseline: 1.2782x; 1.2782x over previous
//
#include <hip/hip_runtime.h>
#include <math.h>

#define N_NODES 50000
#define N_EDGES 1200000
#define IN_DIM  256
#define OUT_DIM 64
#define SLOPE   0.2f
#define SCAN_NB ((N_NODES + 255) / 256)   // 196

// ---------------------------------------------------------------------------
// K1: z = h @ W_fc^T, fused s_src = z@a_src, s_dst = z@a_dst  (unchanged R1)
// ---------------------------------------------------------------------------
__global__ __launch_bounds__(64) void k_gemm(const float* __restrict__ h,
                                             const float* __restrict__ Wfc,
                                             const float* __restrict__ Wattn,
                                             float* __restrict__ z,
                                             float* __restrict__ sS,
                                             float* __restrict__ sD) {
    __shared__ float hl[16 * IN_DIM];
    const int j = threadIdx.x;
    const int nodeBase = blockIdx.x * 16;

    const float4* hsrc = (const float4*)(h + (size_t)nodeBase * IN_DIM);
    float4* hd = (float4*)hl;
    #pragma unroll
    for (int t = 0; t < 16; ++t) hd[j + t * 64] = hsrc[j + t * 64];
    __syncthreads();

    const float4* Wrow = (const float4*)(Wfc + (size_t)j * IN_DIM);
    float acc[16];
    #pragma unroll
    for (int r = 0; r < 16; ++r) acc[r] = 0.f;

    for (int kb = 0; kb < 4; ++kb) {
        float4 w[16];
        #pragma unroll
        for (int t = 0; t < 16; ++t) w[t] = Wrow[kb * 16 + t];
        #pragma unroll
        for (int r = 0; r < 16; ++r) {
            const float* hr = hl + r * IN_DIM + kb * 64;
            float a = acc[r];
            #pragma unroll
            for (int t = 0; t < 16; ++t) {
                float4 hv = ((const float4*)hr)[t];
                a += w[t].x * hv.x; a += w[t].y * hv.y;
                a += w[t].z * hv.z; a += w[t].w * hv.w;
            }
            acc[r] = a;
        }
    }

    const float aS = Wattn[j];
    const float aD = Wattn[OUT_DIM + j];
    #pragma unroll
    for (int r = 0; r < 16; ++r) {
        const size_t node = (size_t)nodeBase + r;
        z[node * OUT_DIM + j] = acc[r];
        float ss = acc[r] * aS;
        float sd = acc[r] * aD;
        #pragma unroll
        for (int off = 32; off > 0; off >>= 1) {
            ss += __shfl_down(ss, off);
            sd += __shfl_down(sd, off);
        }
        if (j == 0) { sS[node] = ss; sD[node] = sd; }
    }
}

// ---------------------------------------------------------------------------
// K2: histogram of dst
// ---------------------------------------------------------------------------
__global__ __launch_bounds__(256) void k_hist(const int* __restrict__ dst,
                                              int* __restrict__ count) {
    int e = blockIdx.x * 256 + threadIdx.x;
    if (e >= N_EDGES) return;
    atomicAdd(count + dst[e], 1);
}

// ---------------------------------------------------------------------------
// K3a/b/c: exclusive scan of count[50000] -> rowptr[50001]
// ---------------------------------------------------------------------------
__global__ __launch_bounds__(256) void k_scan1(const int* __restrict__ count,
                                               int* __restrict__ bsum) {
    __shared__ int tmp[256];
    int t = threadIdx.x, i = blockIdx.x * 256 + t;
    int v = (i < N_NODES) ? count[i] : 0;
    tmp[t] = v; __syncthreads();
    for (int off = 128; off > 0; off >>= 1) {
        if (t < off) tmp[t] += tmp[t + off];
        __syncthreads();
    }
    if (t == 0) bsum[blockIdx.x] = tmp[0];
}

__global__ __launch_bounds__(256) void k_scan2(int* __restrict__ bsum,
                                               int* __restrict__ boff) {
    __shared__ int tmp[256];
    int t = threadIdx.x;
    int v = (t < SCAN_NB) ? bsum[t] : 0;
    tmp[t] = v; __syncthreads();
    for (int off = 1; off < 256; off <<= 1) {
        int x = (t >= off) ? tmp[t - off] : 0;
        __syncthreads();
        tmp[t] += x;
        __syncthreads();
    }
    if (t < SCAN_NB) boff[t] = tmp[t] - v;   // exclusive
}

__global__ __launch_bounds__(256) void k_scan3(const int* __restrict__ count,
                                               const int* __restrict__ boff,
                                               int* __restrict__ rowptr) {
    __shared__ int tmp[256];
    int t = threadIdx.x, i = blockIdx.x * 256 + t;
    int v = (i < N_NODES) ? count[i] : 0;
    tmp[t] = v; __syncthreads();
    for (int off = 1; off < 256; off <<= 1) {
        int x = (t >= off) ? tmp[t - off] : 0;
        __syncthreads();
        tmp[t] += x;
        __syncthreads();
    }
    if (i < N_NODES) rowptr[i] = boff[blockIdx.x] + tmp[t] - v;
    if (i == 0) rowptr[N_NODES] = N_EDGES;
}

// ---------------------------------------------------------------------------
// K4: per-edge: ex = exp(leaky_relu(sS[src]+sD[dst])); denom[dst]+=ex;
//     scatter payload {src, ex} into dst-grouped slot
// ---------------------------------------------------------------------------
__global__ __launch_bounds__(256) void k_scatter(const float* __restrict__ sS,
                                                 const float* __restrict__ sD,
                                                 const int* __restrict__ src,
                                                 const int* __restrict__ dst,
                                                 const int* __restrict__ rowptr,
                                                 int* __restrict__ cursor,
                                                 float* __restrict__ denom,
                                                 float2* __restrict__ payload) {
    int e = blockIdx.x * 256 + threadIdx.x;
    if (e >= N_EDGES) return;
    int s = src[e], d = dst[e];
    float sc = sS[s] + sD[d];
    sc = sc > 0.f ? sc : SLOPE * sc;
    float v = __expf(sc);
    atomicAdd(denom + d, v);
    int idx = rowptr[d] + atomicAdd(cursor + d, 1);
    payload[idx] = make_float2(__int_as_float(s), v);
}

// ---------------------------------------------------------------------------
// K5: one wave per dst node: acc = sum(ex * z[src]) / denom; out = elu(acc)
// ---------------------------------------------------------------------------
__global__ __launch_bounds__(256) void k_aggc(const float* __restrict__ z,
                                              const float2* __restrict__ payload,
                                              const float* __restrict__ denom,
                                              const int* __restrict__ rowptr,
                                              float* __restrict__ out) {
    int node = blockIdx.x * 4 + (threadIdx.x >> 6);
    int lane = threadIdx.x & 63;
    if (node >= N_NODES) return;
    int beg = rowptr[node], end = rowptr[node + 1];
    float acc = 0.f;
    int k = beg;
    for (; k + 1 < end; k += 2) {
        float2 p0 = payload[k];
        float2 p1 = payload[k + 1];
        int s0 = __float_as_int(p0.x);
        int s1 = __float_as_int(p1.x);
        float z0 = z[(size_t)s0 * OUT_DIM + lane];
        float z1 = z[(size_t)s1 * OUT_DIM + lane];
        acc += p0.y * z0;
        acc += p1.y * z1;
    }
    if (k < end) {
        float2 p = payload[k];
        acc += p.y * z[(size_t)__float_as_int(p.x) * OUT_DIM + lane];
    }
    if (end > beg) acc /= denom[node];
    out[(size_t)node * OUT_DIM + lane] = acc > 0.f ? acc : expm1f(acc);
}

extern "C" void kernel_launch(void* const* d_in, const int* in_sizes, int n_in,
                              void* d_out, int out_size, void* d_ws, size_t ws_size,
                              hipStream_t stream) {
    const float* h     = (const float*)d_in[0];
    const float* Wfc   = (const float*)d_in[1];
    const float* Wattn = (const float*)d_in[2];
    const int*   src   = (const int*)d_in[3];
    const int*   dst   = (const int*)d_in[4];
    float* out = (float*)d_out;

    // workspace layout
    char* ws = (char*)d_ws;
    float* z      = (float*)ws;                         // 12.8 MB
    float* sS     = z + (size_t)N_NODES * OUT_DIM;      // 50000
    float* sD     = sS + N_NODES;                       // 50000
    float* denom  = sD + N_NODES;                       // 50000  } zeroed
    int*   count  = (int*)(denom + N_NODES);            // 50000  } together
    int*   cursor = count + N_NODES;                    // 50000  }
    int*   rowptr = cursor + N_NODES;                   // 50001
    int*   bsum   = rowptr + N_NODES + 1;               // 256
    int*   boff   = bsum + 256;                         // 256
    float2* payload = (float2*)(boff + 256);            // 9.6 MB

    // zero denom + count + cursor in one shot (contiguous)
    hipMemsetAsync(denom, 0, (size_t)N_NODES * 3 * sizeof(int), stream);

    k_gemm<<<N_NODES / 16, 64, 0, stream>>>(h, Wfc, Wattn, z, sS, sD);
    k_hist<<<(N_EDGES + 255) / 256, 256, 0, stream>>>(dst, count);
    k_scan1<<<SCAN_NB, 256, 0, stream>>>(count, bsum);
    k_scan2<<<1, 256, 0, stream>>>(bsum, boff);
    k_scan3<<<SCAN_NB, 256, 0, stream>>>(count, boff, rowptr);
    k_scatter<<<(N_EDGES + 255) / 256, 256, 0, stream>>>(sS, sD, src, dst,
                                                         rowptr, cursor, denom, payload);
    k_aggc<<<(N_NODES + 3) / 4, 256, 0, stream>>>(z, payload, denom, rowptr, out);
}

// Round 3
// 320.481 us; speedup vs baseline: 1.3855x; 1.0839x over previous
//
#include <hip/hip_runtime.h>
#include <math.h>

#define N_NODES 50000
#define N_EDGES 1200000
#define IN_DIM  256
#define OUT_DIM 64
#define SLOPE   0.2f
#define SCAN_NB ((N_NODES + 255) / 256)   // 196

// ---------------------------------------------------------------------------
// K1: z = h @ W_fc^T, fused s_src = z@a_src, s_dst = z@a_dst
// ---------------------------------------------------------------------------
__global__ __launch_bounds__(64) void k_gemm(const float* __restrict__ h,
                                             const float* __restrict__ Wfc,
                                             const float* __restrict__ Wattn,
                                             float* __restrict__ z,
                                             float* __restrict__ sS,
                                             float* __restrict__ sD) {
    __shared__ float hl[16 * IN_DIM];
    const int j = threadIdx.x;
    const int nodeBase = blockIdx.x * 16;

    const float4* hsrc = (const float4*)(h + (size_t)nodeBase * IN_DIM);
    float4* hd = (float4*)hl;
    #pragma unroll
    for (int t = 0; t < 16; ++t) hd[j + t * 64] = hsrc[j + t * 64];
    __syncthreads();

    const float4* Wrow = (const float4*)(Wfc + (size_t)j * IN_DIM);
    float acc[16];
    #pragma unroll
    for (int r = 0; r < 16; ++r) acc[r] = 0.f;

    for (int kb = 0; kb < 4; ++kb) {
        float4 w[16];
        #pragma unroll
        for (int t = 0; t < 16; ++t) w[t] = Wrow[kb * 16 + t];
        #pragma unroll
        for (int r = 0; r < 16; ++r) {
            const float* hr = hl + r * IN_DIM + kb * 64;
            float a = acc[r];
            #pragma unroll
            for (int t = 0; t < 16; ++t) {
                float4 hv = ((const float4*)hr)[t];
                a += w[t].x * hv.x; a += w[t].y * hv.y;
                a += w[t].z * hv.z; a += w[t].w * hv.w;
            }
            acc[r] = a;
        }
    }

    const float aS = Wattn[j];
    const float aD = Wattn[OUT_DIM + j];
    #pragma unroll
    for (int r = 0; r < 16; ++r) {
        const size_t node = (size_t)nodeBase + r;
        z[node * OUT_DIM + j] = acc[r];
        float ss = acc[r] * aS;
        float sd = acc[r] * aD;
        #pragma unroll
        for (int off = 32; off > 0; off >>= 1) {
            ss += __shfl_down(ss, off);
            sd += __shfl_down(sd, off);
        }
        if (j == 0) { sS[node] = ss; sD[node] = sd; }
    }
}

// ---------------------------------------------------------------------------
// K2: histogram of dst
// ---------------------------------------------------------------------------
__global__ __launch_bounds__(256) void k_hist(const int* __restrict__ dst,
                                              int* __restrict__ count) {
    int e = blockIdx.x * 256 + threadIdx.x;
    if (e >= N_EDGES) return;
    atomicAdd(count + dst[e], 1);
}

// ---------------------------------------------------------------------------
// K3a/b/c: exclusive scan of count[50000] -> rowptr[50001]; cursor = rowptr
// ---------------------------------------------------------------------------
__global__ __launch_bounds__(256) void k_scan1(const int* __restrict__ count,
                                               int* __restrict__ bsum) {
    __shared__ int tmp[256];
    int t = threadIdx.x, i = blockIdx.x * 256 + t;
    int v = (i < N_NODES) ? count[i] : 0;
    tmp[t] = v; __syncthreads();
    for (int off = 128; off > 0; off >>= 1) {
        if (t < off) tmp[t] += tmp[t + off];
        __syncthreads();
    }
    if (t == 0) bsum[blockIdx.x] = tmp[0];
}

__global__ __launch_bounds__(256) void k_scan2(int* __restrict__ bsum,
                                               int* __restrict__ boff) {
    __shared__ int tmp[256];
    int t = threadIdx.x;
    int v = (t < SCAN_NB) ? bsum[t] : 0;
    tmp[t] = v; __syncthreads();
    for (int off = 1; off < 256; off <<= 1) {
        int x = (t >= off) ? tmp[t - off] : 0;
        __syncthreads();
        tmp[t] += x;
        __syncthreads();
    }
    if (t < SCAN_NB) boff[t] = tmp[t] - v;   // exclusive
}

__global__ __launch_bounds__(256) void k_scan3(const int* __restrict__ count,
                                               const int* __restrict__ boff,
                                               int* __restrict__ rowptr,
                                               int* __restrict__ cursor) {
    __shared__ int tmp[256];
    int t = threadIdx.x, i = blockIdx.x * 256 + t;
    int v = (i < N_NODES) ? count[i] : 0;
    tmp[t] = v; __syncthreads();
    for (int off = 1; off < 256; off <<= 1) {
        int x = (t >= off) ? tmp[t - off] : 0;
        __syncthreads();
        tmp[t] += x;
        __syncthreads();
    }
    if (i < N_NODES) {
        int rp = boff[blockIdx.x] + tmp[t] - v;
        rowptr[i] = rp;
        cursor[i] = rp;
    }
    if (i == 0) rowptr[N_NODES] = N_EDGES;
}

// ---------------------------------------------------------------------------
// K4: minimal scatter: perm[cursor[d]++] = src  (2 edges/thread for ILP)
// ---------------------------------------------------------------------------
__global__ __launch_bounds__(256) void k_scatter(const int* __restrict__ src,
                                                 const int* __restrict__ dst,
                                                 int* __restrict__ cursor,
                                                 int* __restrict__ perm) {
    int t = blockIdx.x * 256 + threadIdx.x;
    if (t >= N_EDGES / 2) return;
    int2 s2 = ((const int2*)src)[t];
    int2 d2 = ((const int2*)dst)[t];
    int i0 = atomicAdd(cursor + d2.x, 1);
    int i1 = atomicAdd(cursor + d2.y, 1);
    perm[i0] = s2.x;
    perm[i1] = s2.y;
}

// ---------------------------------------------------------------------------
// K5: one wave per dst node: recompute ex per edge, acc = sum(ex*z[src]),
//     denom in-register, out = elu(acc/denom)
// ---------------------------------------------------------------------------
__global__ __launch_bounds__(256) void k_aggc(const float* __restrict__ z,
                                              const int* __restrict__ perm,
                                              const float* __restrict__ sS,
                                              const float* __restrict__ sD,
                                              const int* __restrict__ rowptr,
                                              float* __restrict__ out) {
    int node = blockIdx.x * 4 + (threadIdx.x >> 6);
    int lane = threadIdx.x & 63;
    if (node >= N_NODES) return;
    int beg = rowptr[node], end = rowptr[node + 1];
    const float sdn = sD[node];
    float acc = 0.f;
    float den = 0.f;
    int k = beg;
    for (; k + 1 < end; k += 2) {
        int s0 = perm[k];
        int s1 = perm[k + 1];
        float e0 = sS[s0] + sdn;
        float e1 = sS[s1] + sdn;
        e0 = e0 > 0.f ? e0 : SLOPE * e0;
        e1 = e1 > 0.f ? e1 : SLOPE * e1;
        float v0 = __expf(e0);
        float v1 = __expf(e1);
        float z0 = z[(size_t)s0 * OUT_DIM + lane];
        float z1 = z[(size_t)s1 * OUT_DIM + lane];
        den += v0 + v1;
        acc += v0 * z0;
        acc += v1 * z1;
    }
    if (k < end) {
        int s = perm[k];
        float e = sS[s] + sdn;
        e = e > 0.f ? e : SLOPE * e;
        float v = __expf(e);
        den += v;
        acc += v * z[(size_t)s * OUT_DIM + lane];
    }
    if (end > beg) acc /= den;
    out[(size_t)node * OUT_DIM + lane] = acc > 0.f ? acc : expm1f(acc);
}

extern "C" void kernel_launch(void* const* d_in, const int* in_sizes, int n_in,
                              void* d_out, int out_size, void* d_ws, size_t ws_size,
                              hipStream_t stream) {
    const float* h     = (const float*)d_in[0];
    const float* Wfc   = (const float*)d_in[1];
    const float* Wattn = (const float*)d_in[2];
    const int*   src   = (const int*)d_in[3];
    const int*   dst   = (const int*)d_in[4];
    float* out = (float*)d_out;

    // workspace layout
    char* ws = (char*)d_ws;
    float* z      = (float*)ws;                         // 12.8 MB
    float* sS     = z + (size_t)N_NODES * OUT_DIM;      // 50000
    float* sD     = sS + N_NODES;                       // 50000
    int*   count  = (int*)(sD + N_NODES);               // 50000 (zeroed)
    int*   cursor = count + N_NODES;                    // 50000
    int*   rowptr = cursor + N_NODES;                   // 50001
    int*   bsum   = rowptr + N_NODES + 1;               // 256
    int*   boff   = bsum + 256;                         // 256
    int*   perm   = boff + 256;                         // 4.8 MB

    hipMemsetAsync(count, 0, (size_t)N_NODES * sizeof(int), stream);

    k_hist<<<(N_EDGES + 255) / 256, 256, 0, stream>>>(dst, count);
    k_scan1<<<SCAN_NB, 256, 0, stream>>>(count, bsum);
    k_scan2<<<1, 256, 0, stream>>>(bsum, boff);
    k_scan3<<<SCAN_NB, 256, 0, stream>>>(count, boff, rowptr, cursor);
    k_scatter<<<(N_EDGES / 2 + 255) / 256, 256, 0, stream>>>(src, dst, cursor, perm);
    k_gemm<<<N_NODES / 16, 64, 0, stream>>>(h, Wfc, Wattn, z, sS, sD);
    k_aggc<<<(N_NODES + 3) / 4, 256, 0, stream>>>(z, perm, sS, sD, rowptr, out);
}

// Round 4
// 133.545 us; speedup vs baseline: 3.3249x; 2.3998x over previous
//
#include <hip/hip_runtime.h>
#include <math.h>

#define N_NODES 50000
#define N_EDGES 1200000
#define IN_DIM  256
#define OUT_DIM 64
#define SLOPE   0.2f
#define NBKT    256          // coarse buckets, bucket = dst / 196
#define BNODES  196          // nodes per bucket (last bucket: 20)
#define EPB     4096         // edges per k_bin block
#define BCAP    5632         // max edges per bucket (mean 4704, +13.5 sigma)

typedef unsigned int   uint;
typedef unsigned short ushort;
typedef float  f32x4  __attribute__((ext_vector_type(4)));
typedef short  short8 __attribute__((ext_vector_type(8)));

__device__ inline ushort bf16_rne(float f) {
    uint u = __float_as_uint(f);
    u += 0x7FFF + ((u >> 16) & 1);
    return (ushort)(u >> 16);
}
__device__ inline float bf16_f32(ushort s) {
    return __uint_as_float(((uint)s) << 16);
}

// ---------------------------------------------------------------------------
// K0: W_fc -> bf16 hi/lo split (for ~f32-accurate MFMA)
// ---------------------------------------------------------------------------
__global__ __launch_bounds__(256) void k_prep(const float* __restrict__ Wfc,
                                              ushort* __restrict__ Whi,
                                              ushort* __restrict__ Wlo) {
    int i = blockIdx.x * 256 + threadIdx.x;
    if (i >= OUT_DIM * IN_DIM) return;
    float f = Wfc[i];
    ushort hi = bf16_rne(f);
    Whi[i] = hi;
    Wlo[i] = bf16_rne(f - bf16_f32(hi));
}

// ---------------------------------------------------------------------------
// K1: z = h @ W^T via mfma_f32_16x16x32_bf16, split-bf16 (hihi + lohi + hilo).
// One wave / 16 nodes. No LDS: per-lane direct A loads (lines fully used).
// Fused sS = z@aS, sD = z@aD. z stored bf16.
// A-frag: lane l holds A[l&15][(l>>4)*8+i]; B-frag: B[(l>>4)*8+i][l&15];
// C-frag: reg r -> C[(l>>4)*4+r][l&15]   (m89-verified mapping)
// ---------------------------------------------------------------------------
__global__ __launch_bounds__(64) void k_gemm(const float* __restrict__ h,
                                             const ushort* __restrict__ Whi,
                                             const ushort* __restrict__ Wlo,
                                             const float* __restrict__ Wattn,
                                             ushort* __restrict__ zb,
                                             float* __restrict__ sS,
                                             float* __restrict__ sD) {
    const int l   = threadIdx.x;
    const int r16 = l & 15;          // A-row / B-col within tile
    const int g   = l >> 4;          // k-subgroup
    const int base = blockIdx.x * 16;

    const float*  ha = h   + (size_t)(base + r16) * IN_DIM + g * 8;
    const ushort* wh = Whi + (size_t)r16 * IN_DIM + g * 8;
    const ushort* wl = Wlo + (size_t)r16 * IN_DIM + g * 8;

    f32x4 c[4] = {{0,0,0,0},{0,0,0,0},{0,0,0,0},{0,0,0,0}};

    #pragma unroll
    for (int ks = 0; ks < 8; ++ks) {             // K steps of 32
        float4 a0 = *(const float4*)(ha + ks * 32);
        float4 a1 = *(const float4*)(ha + ks * 32 + 4);
        float af[8] = {a0.x, a0.y, a0.z, a0.w, a1.x, a1.y, a1.z, a1.w};
        short8 ahi, alo;
        #pragma unroll
        for (int i = 0; i < 8; ++i) {
            ushort hi = bf16_rne(af[i]);
            ahi[i] = (short)hi;
            alo[i] = (short)bf16_rne(af[i] - bf16_f32(hi));
        }
        #pragma unroll
        for (int n = 0; n < 4; ++n) {            // 4 j-tiles of 16
            short8 bh = *(const short8*)(wh + n * 16 * IN_DIM + ks * 32);
            short8 bl = *(const short8*)(wl + n * 16 * IN_DIM + ks * 32);
            c[n] = __builtin_amdgcn_mfma_f32_16x16x32_bf16(ahi, bh, c[n], 0, 0, 0);
            c[n] = __builtin_amdgcn_mfma_f32_16x16x32_bf16(alo, bh, c[n], 0, 0, 0);
            c[n] = __builtin_amdgcn_mfma_f32_16x16x32_bf16(ahi, bl, c[n], 0, 0, 0);
        }
    }

    float aSv[4], aDv[4];
    #pragma unroll
    for (int n = 0; n < 4; ++n) {
        aSv[n] = Wattn[n * 16 + r16];
        aDv[n] = Wattn[OUT_DIM + n * 16 + r16];
    }
    #pragma unroll
    for (int r = 0; r < 4; ++r) {
        int node = base + g * 4 + r;
        float ss = 0.f, sd = 0.f;
        #pragma unroll
        for (int n = 0; n < 4; ++n) {
            float v = c[n][r];
            zb[(size_t)node * OUT_DIM + n * 16 + r16] = bf16_rne(v);
            ss += v * aSv[n];
            sd += v * aDv[n];
        }
        ss += __shfl_xor(ss, 1); ss += __shfl_xor(ss, 2);
        ss += __shfl_xor(ss, 4); ss += __shfl_xor(ss, 8);
        sd += __shfl_xor(sd, 1); sd += __shfl_xor(sd, 2);
        sd += __shfl_xor(sd, 4); sd += __shfl_xor(sd, 8);
        if (r16 == 0) { sS[node] = ss; sD[node] = sd; }
    }
}

// ---------------------------------------------------------------------------
// K2: coarse bucket histogram (bucket = dst/196)
// ---------------------------------------------------------------------------
__global__ __launch_bounds__(256) void k_hist(const int* __restrict__ dst,
                                              int* __restrict__ gcount) {
    __shared__ int lh[NBKT];
    int t = threadIdx.x;
    lh[t] = 0;
    __syncthreads();
    for (int e = blockIdx.x * 256 + t; e < N_EDGES; e += 256 * 256)
        atomicAdd(&lh[dst[e] / BNODES], 1);
    __syncthreads();
    atomicAdd(&gcount[t], lh[t]);
}

// ---------------------------------------------------------------------------
// K3: scan 256 counts -> bucketPtr[257]; bucketCur = bucketPtr
// ---------------------------------------------------------------------------
__global__ __launch_bounds__(256) void k_scan(const int* __restrict__ gcount,
                                              int* __restrict__ bucketPtr,
                                              int* __restrict__ bucketCur) {
    __shared__ int sc[256];
    int t = threadIdx.x;
    int v = gcount[t];
    sc[t] = v; __syncthreads();
    for (int off = 1; off < 256; off <<= 1) {
        int x = (t >= off) ? sc[t - off] : 0;
        __syncthreads(); sc[t] += x; __syncthreads();
    }
    int excl = sc[t] - v;
    bucketPtr[t] = excl;
    bucketCur[t] = excl;
    if (t == 255) bucketPtr[256] = N_EDGES;
}

// ---------------------------------------------------------------------------
// K4: LDS-staged multisplit into 256 buckets. pack = (b<<24)|(dl<<16)|src.
// Random writes confined to LDS; global writes are per-bucket coalesced runs.
// ---------------------------------------------------------------------------
__global__ __launch_bounds__(256) void k_bin(const int* __restrict__ src,
                                             const int* __restrict__ dst,
                                             int* __restrict__ bucketCur,
                                             uint* __restrict__ binned) {
    __shared__ uint staged[EPB];
    __shared__ int lhist[NBKT], lscan[NBKT], lcur[NBKT], gbaseL[NBKT], sc[NBKT];
    int t = threadIdx.x;
    int base = blockIdx.x * EPB;
    int n = min(EPB, N_EDGES - base);
    lhist[t] = 0;
    __syncthreads();
    #pragma unroll
    for (int k = 0; k < EPB / 256; ++k) {
        int i = k * 256 + t;
        if (i < n) atomicAdd(&lhist[dst[base + i] / BNODES], 1);
    }
    __syncthreads();
    int v = lhist[t]; sc[t] = v; __syncthreads();
    for (int off = 1; off < 256; off <<= 1) {
        int x = (t >= off) ? sc[t - off] : 0;
        __syncthreads(); sc[t] += x; __syncthreads();
    }
    int excl = sc[t] - v;
    lscan[t] = excl; lcur[t] = excl;
    gbaseL[t] = atomicAdd(&bucketCur[t], v);
    __syncthreads();
    #pragma unroll
    for (int k = 0; k < EPB / 256; ++k) {
        int i = k * 256 + t;
        if (i < n) {
            int d = dst[base + i], s = src[base + i];
            int b = d / BNODES, dl = d - b * BNODES;
            int slot = atomicAdd(&lcur[b], 1);
            staged[slot] = ((uint)b << 24) | ((uint)dl << 16) | (uint)s;
        }
    }
    __syncthreads();
    #pragma unroll
    for (int k = 0; k < EPB / 256; ++k) {
        int i = k * 256 + t;
        if (i < n) {
            uint w = staged[i];
            int b = (int)(w >> 24);
            binned[gbaseL[b] + (i - lscan[b])] = w;
        }
    }
}

// ---------------------------------------------------------------------------
// K5: per-bucket LDS counting sort by dst-local -> srcSorted (u16) + rowptrFine
// ---------------------------------------------------------------------------
__global__ __launch_bounds__(256) void k_sort(const uint* __restrict__ binned,
                                              const int* __restrict__ bucketPtr,
                                              ushort* __restrict__ srcSorted,
                                              int* __restrict__ rowptrFine) {
    __shared__ ushort lsrc[BCAP];
    __shared__ int lhist[256], lscan[256], lcur[256], sc[256];
    int b = blockIdx.x, t = threadIdx.x;
    int beg = bucketPtr[b], end = bucketPtr[b + 1], n = end - beg;
    lhist[t] = 0;
    __syncthreads();
    for (int i = t; i < n; i += 256)
        atomicAdd(&lhist[(binned[beg + i] >> 16) & 0xFF], 1);
    __syncthreads();
    int v = lhist[t]; sc[t] = v; __syncthreads();
    for (int off = 1; off < 256; off <<= 1) {
        int x = (t >= off) ? sc[t - off] : 0;
        __syncthreads(); sc[t] += x; __syncthreads();
    }
    int excl = sc[t] - v;
    lscan[t] = excl; lcur[t] = excl;
    int node = b * BNODES + t;
    if (t < BNODES && node < N_NODES) rowptrFine[node] = beg + excl;
    if (b == NBKT - 1 && t == 0) rowptrFine[N_NODES] = N_EDGES;
    __syncthreads();
    for (int i = t; i < n; i += 256) {
        uint w = binned[beg + i];
        int dl = (int)((w >> 16) & 0xFF);
        int slot = atomicAdd(&lcur[dl], 1);
        lsrc[slot] = (ushort)(w & 0xFFFF);
    }
    __syncthreads();
    for (int i = t; i < n; i += 256) srcSorted[beg + i] = lsrc[i];
}

// ---------------------------------------------------------------------------
// K6: one wave per dst node: acc = sum(exp(leaky(sS[s]+sD))*z_bf16[s]),
// den in register, out = elu(acc/den). Unroll 4 for latency hiding.
// ---------------------------------------------------------------------------
__global__ __launch_bounds__(256) void k_aggc(const ushort* __restrict__ zb,
                                              const ushort* __restrict__ srcSorted,
                                              const float* __restrict__ sS,
                                              const float* __restrict__ sD,
                                              const int* __restrict__ rowptr,
                                              float* __restrict__ out) {
    int node = blockIdx.x * 4 + (threadIdx.x >> 6);
    int lane = threadIdx.x & 63;
    int beg = rowptr[node], end = rowptr[node + 1];
    const float sdn = sD[node];
    float acc = 0.f, den = 0.f;
    int k = beg;
    for (; k + 4 <= end; k += 4) {
        int s0 = srcSorted[k], s1 = srcSorted[k + 1];
        int s2 = srcSorted[k + 2], s3 = srcSorted[k + 3];
        float e0 = sS[s0] + sdn, e1 = sS[s1] + sdn;
        float e2 = sS[s2] + sdn, e3 = sS[s3] + sdn;
        e0 = e0 > 0.f ? e0 : SLOPE * e0;
        e1 = e1 > 0.f ? e1 : SLOPE * e1;
        e2 = e2 > 0.f ? e2 : SLOPE * e2;
        e3 = e3 > 0.f ? e3 : SLOPE * e3;
        float v0 = __expf(e0), v1 = __expf(e1), v2 = __expf(e2), v3 = __expf(e3);
        float z0 = bf16_f32(zb[(size_t)s0 * OUT_DIM + lane]);
        float z1 = bf16_f32(zb[(size_t)s1 * OUT_DIM + lane]);
        float z2 = bf16_f32(zb[(size_t)s2 * OUT_DIM + lane]);
        float z3 = bf16_f32(zb[(size_t)s3 * OUT_DIM + lane]);
        acc += v0 * z0; acc += v1 * z1; acc += v2 * z2; acc += v3 * z3;
        den += v0 + v1 + v2 + v3;
    }
    for (; k < end; ++k) {
        int s = srcSorted[k];
        float e = sS[s] + sdn;
        e = e > 0.f ? e : SLOPE * e;
        float v = __expf(e);
        acc += v * bf16_f32(zb[(size_t)s * OUT_DIM + lane]);
        den += v;
    }
    float r = den > 0.f ? acc / den : 0.f;
    out[(size_t)node * OUT_DIM + lane] = r > 0.f ? r : expm1f(r);
}

static inline char* alignup(char* p) {
    return (char*)(((uintptr_t)p + 63) & ~(uintptr_t)63);
}

extern "C" void kernel_launch(void* const* d_in, const int* in_sizes, int n_in,
                              void* d_out, int out_size, void* d_ws, size_t ws_size,
                              hipStream_t stream) {
    const float* h     = (const float*)d_in[0];
    const float* Wfc   = (const float*)d_in[1];
    const float* Wattn = (const float*)d_in[2];
    const int*   src   = (const int*)d_in[3];
    const int*   dst   = (const int*)d_in[4];
    float* out = (float*)d_out;

    // workspace layout (64B-aligned regions)
    char* p = (char*)d_ws;
    uint*   binned    = (uint*)p;             p = alignup(p + (size_t)N_EDGES * 4);
    int*    rowptrF   = (int*)p;              p = alignup(p + (size_t)(N_NODES + 1) * 4);
    float*  sS        = (float*)p;            p = alignup(p + (size_t)N_NODES * 4);
    float*  sD        = (float*)p;            p = alignup(p + (size_t)N_NODES * 4);
    int*    gcount    = (int*)p;              p = alignup(p + NBKT * 4);
    int*    bucketPtr = (int*)p;              p = alignup(p + (NBKT + 1) * 4);
    int*    bucketCur = (int*)p;              p = alignup(p + NBKT * 4);
    ushort* Whi       = (ushort*)p;           p = alignup(p + OUT_DIM * IN_DIM * 2);
    ushort* Wlo       = (ushort*)p;           p = alignup(p + OUT_DIM * IN_DIM * 2);
    ushort* zb        = (ushort*)p;           p = alignup(p + (size_t)N_NODES * OUT_DIM * 2);
    ushort* srcSorted = (ushort*)p;

    hipMemsetAsync(gcount, 0, NBKT * sizeof(int), stream);

    k_prep<<<(OUT_DIM * IN_DIM + 255) / 256, 256, 0, stream>>>(Wfc, Whi, Wlo);
    k_hist<<<256, 256, 0, stream>>>(dst, gcount);
    k_scan<<<1, 256, 0, stream>>>(gcount, bucketPtr, bucketCur);
    k_bin<<<(N_EDGES + EPB - 1) / EPB, 256, 0, stream>>>(src, dst, bucketCur, binned);
    k_sort<<<NBKT, 256, 0, stream>>>(binned, bucketPtr, srcSorted, rowptrF);
    k_gemm<<<N_NODES / 16, 64, 0, stream>>>(h, Whi, Wlo, Wattn, zb, sS, sD);
    k_aggc<<<N_NODES / 4, 256, 0, stream>>>(zb, srcSorted, sS, sD, rowptrF, out);
}

// Round 5
// 132.131 us; speedup vs baseline: 3.3605x; 1.0107x over previous
//
#include <hip/hip_runtime.h>
#include <math.h>

#define N_NODES 50000
#define N_EDGES 1200000
#define IN_DIM  256
#define OUT_DIM 64
#define SLOPE   0.2f
#define NBKT    256          // coarse buckets, bucket = dst / 196
#define BNODES  196          // nodes per bucket (last bucket: 20)
#define EPB     4096         // edges per k_bin block
#define BCAP    5632         // max edges per bucket (mean 4704, +13.5 sigma)

typedef unsigned int   uint;
typedef unsigned short ushort;
typedef float  f32x4  __attribute__((ext_vector_type(4)));
typedef short  short8 __attribute__((ext_vector_type(8)));

__device__ inline ushort bf16_rne(float f) {
    uint u = __float_as_uint(f);
    u += 0x7FFF + ((u >> 16) & 1);
    return (ushort)(u >> 16);
}
__device__ inline float bf16_f32(ushort s) {
    return __uint_as_float(((uint)s) << 16);
}
__device__ inline ushort f32_f16(float f) {
    _Float16 h = (_Float16)f;
    return __builtin_bit_cast(ushort, h);
}
__device__ inline float f16_f32(ushort u) {
    return (float)__builtin_bit_cast(_Float16, u);
}

// ---------------------------------------------------------------------------
// K0: blocks 0..255: coarse dst histogram; blocks 256..319: W->bf16 hi/lo prep
// ---------------------------------------------------------------------------
__global__ __launch_bounds__(256) void k_prep_hist(const float* __restrict__ Wfc,
                                                   ushort* __restrict__ Whi,
                                                   ushort* __restrict__ Wlo,
                                                   const int* __restrict__ dst,
                                                   int* __restrict__ gcount) {
    if (blockIdx.x >= 256) {
        int i = (blockIdx.x - 256) * 256 + threadIdx.x;
        if (i < OUT_DIM * IN_DIM) {
            float f = Wfc[i];
            ushort hi = bf16_rne(f);
            Whi[i] = hi;
            Wlo[i] = bf16_rne(f - bf16_f32(hi));
        }
        return;
    }
    __shared__ int lh[NBKT];
    int t = threadIdx.x;
    lh[t] = 0;
    __syncthreads();
    for (int e = blockIdx.x * 256 + t; e < N_EDGES; e += 256 * 256)
        atomicAdd(&lh[dst[e] / BNODES], 1);
    __syncthreads();
    atomicAdd(&gcount[t], lh[t]);
}

// ---------------------------------------------------------------------------
// K1: z = h @ W^T via mfma_f32_16x16x32_bf16, split-bf16 (hihi + lohi + hilo).
// One wave / 16 nodes, no LDS. Fused sS/sD. z stored f16.
// ---------------------------------------------------------------------------
__global__ __launch_bounds__(64) void k_gemm(const float* __restrict__ h,
                                             const ushort* __restrict__ Whi,
                                             const ushort* __restrict__ Wlo,
                                             const float* __restrict__ Wattn,
                                             ushort* __restrict__ zh,
                                             float* __restrict__ sS,
                                             float* __restrict__ sD) {
    const int l   = threadIdx.x;
    const int r16 = l & 15;
    const int g   = l >> 4;
    const int base = blockIdx.x * 16;

    const float*  ha = h   + (size_t)(base + r16) * IN_DIM + g * 8;
    const ushort* wh = Whi + (size_t)r16 * IN_DIM + g * 8;
    const ushort* wl = Wlo + (size_t)r16 * IN_DIM + g * 8;

    f32x4 c[4] = {{0,0,0,0},{0,0,0,0},{0,0,0,0},{0,0,0,0}};

    #pragma unroll
    for (int ks = 0; ks < 8; ++ks) {
        float4 a0 = *(const float4*)(ha + ks * 32);
        float4 a1 = *(const float4*)(ha + ks * 32 + 4);
        float af[8] = {a0.x, a0.y, a0.z, a0.w, a1.x, a1.y, a1.z, a1.w};
        short8 ahi, alo;
        #pragma unroll
        for (int i = 0; i < 8; ++i) {
            ushort hi = bf16_rne(af[i]);
            ahi[i] = (short)hi;
            alo[i] = (short)bf16_rne(af[i] - bf16_f32(hi));
        }
        #pragma unroll
        for (int n = 0; n < 4; ++n) {
            short8 bh = *(const short8*)(wh + n * 16 * IN_DIM + ks * 32);
            short8 bl = *(const short8*)(wl + n * 16 * IN_DIM + ks * 32);
            c[n] = __builtin_amdgcn_mfma_f32_16x16x32_bf16(ahi, bh, c[n], 0, 0, 0);
            c[n] = __builtin_amdgcn_mfma_f32_16x16x32_bf16(alo, bh, c[n], 0, 0, 0);
            c[n] = __builtin_amdgcn_mfma_f32_16x16x32_bf16(ahi, bl, c[n], 0, 0, 0);
        }
    }

    float aSv[4], aDv[4];
    #pragma unroll
    for (int n = 0; n < 4; ++n) {
        aSv[n] = Wattn[n * 16 + r16];
        aDv[n] = Wattn[OUT_DIM + n * 16 + r16];
    }
    #pragma unroll
    for (int r = 0; r < 4; ++r) {
        int node = base + g * 4 + r;
        float ss = 0.f, sd = 0.f;
        #pragma unroll
        for (int n = 0; n < 4; ++n) {
            float v = c[n][r];
            zh[(size_t)node * OUT_DIM + n * 16 + r16] = f32_f16(v);
            ss += v * aSv[n];
            sd += v * aDv[n];
        }
        ss += __shfl_xor(ss, 1); ss += __shfl_xor(ss, 2);
        ss += __shfl_xor(ss, 4); ss += __shfl_xor(ss, 8);
        sd += __shfl_xor(sd, 1); sd += __shfl_xor(sd, 2);
        sd += __shfl_xor(sd, 4); sd += __shfl_xor(sd, 8);
        if (r16 == 0) { sS[node] = ss; sD[node] = sd; }
    }
}

// ---------------------------------------------------------------------------
// K2: scan 256 counts -> bucketPtr[257]; bucketCur = bucketPtr
// ---------------------------------------------------------------------------
__global__ __launch_bounds__(256) void k_scan(const int* __restrict__ gcount,
                                              int* __restrict__ bucketPtr,
                                              int* __restrict__ bucketCur) {
    __shared__ int sc[256];
    int t = threadIdx.x;
    int v = gcount[t];
    sc[t] = v; __syncthreads();
    for (int off = 1; off < 256; off <<= 1) {
        int x = (t >= off) ? sc[t - off] : 0;
        __syncthreads(); sc[t] += x; __syncthreads();
    }
    int excl = sc[t] - v;
    bucketPtr[t] = excl;
    bucketCur[t] = excl;
    if (t == 255) bucketPtr[256] = N_EDGES;
}

// ---------------------------------------------------------------------------
// K3: LDS-staged multisplit into 256 buckets. pack = (b<<24)|(dl<<16)|src.
// ---------------------------------------------------------------------------
__global__ __launch_bounds__(256) void k_bin(const int* __restrict__ src,
                                             const int* __restrict__ dst,
                                             int* __restrict__ bucketCur,
                                             uint* __restrict__ binned) {
    __shared__ uint staged[EPB];
    __shared__ int lhist[NBKT], lscan[NBKT], lcur[NBKT], gbaseL[NBKT], sc[NBKT];
    int t = threadIdx.x;
    int base = blockIdx.x * EPB;
    int n = min(EPB, N_EDGES - base);
    lhist[t] = 0;
    __syncthreads();
    #pragma unroll
    for (int k = 0; k < EPB / 256; ++k) {
        int i = k * 256 + t;
        if (i < n) atomicAdd(&lhist[dst[base + i] / BNODES], 1);
    }
    __syncthreads();
    int v = lhist[t]; sc[t] = v; __syncthreads();
    for (int off = 1; off < 256; off <<= 1) {
        int x = (t >= off) ? sc[t - off] : 0;
        __syncthreads(); sc[t] += x; __syncthreads();
    }
    int excl = sc[t] - v;
    lscan[t] = excl; lcur[t] = excl;
    gbaseL[t] = atomicAdd(&bucketCur[t], v);
    __syncthreads();
    #pragma unroll
    for (int k = 0; k < EPB / 256; ++k) {
        int i = k * 256 + t;
        if (i < n) {
            int d = dst[base + i], s = src[base + i];
            int b = d / BNODES, dl = d - b * BNODES;
            int slot = atomicAdd(&lcur[b], 1);
            staged[slot] = ((uint)b << 24) | ((uint)dl << 16) | (uint)s;
        }
    }
    __syncthreads();
    #pragma unroll
    for (int k = 0; k < EPB / 256; ++k) {
        int i = k * 256 + t;
        if (i < n) {
            uint w = staged[i];
            int b = (int)(w >> 24);
            binned[gbaseL[b] + (i - lscan[b])] = w;
        }
    }
}

// ---------------------------------------------------------------------------
// K4: per-bucket LDS counting sort by dst-local; computes ex=exp(leaky(.))
// per edge ONCE (f16), per-node denom via LDS atomics, emits packed
// (src<<16)|ex_f16 and exact rowptrFine.
// ---------------------------------------------------------------------------
__global__ __launch_bounds__(256) void k_sort(const uint* __restrict__ binned,
                                              const int* __restrict__ bucketPtr,
                                              const float* __restrict__ sS,
                                              const float* __restrict__ sD,
                                              uint* __restrict__ srcEx,
                                              float* __restrict__ denom,
                                              int* __restrict__ rowptrFine) {
    __shared__ ushort lsrc[BCAP];
    __shared__ ushort lex[BCAP];
    __shared__ int lhist[256], lcur[256], sc[256];
    __shared__ float ldsD[BNODES], lden[BNODES];
    int b = blockIdx.x, t = threadIdx.x;
    int beg = bucketPtr[b], end = bucketPtr[b + 1], n = end - beg;
    int node = b * BNODES + t;
    lhist[t] = 0;
    if (t < BNODES) {
        ldsD[t] = (node < N_NODES) ? sD[node] : 0.f;
        lden[t] = 0.f;
    }
    __syncthreads();
    for (int i = t; i < n; i += 256)
        atomicAdd(&lhist[(binned[beg + i] >> 16) & 0xFF], 1);
    __syncthreads();
    int v = lhist[t]; sc[t] = v; __syncthreads();
    for (int off = 1; off < 256; off <<= 1) {
        int x = (t >= off) ? sc[t - off] : 0;
        __syncthreads(); sc[t] += x; __syncthreads();
    }
    int excl = sc[t] - v;
    lcur[t] = excl;
    if (t < BNODES && node < N_NODES) rowptrFine[node] = beg + excl;
    if (b == NBKT - 1 && t == 0) rowptrFine[N_NODES] = N_EDGES;
    __syncthreads();
    for (int i = t; i < n; i += 256) {
        uint w = binned[beg + i];
        int dl = (int)((w >> 16) & 0xFF);
        int s  = (int)(w & 0xFFFF);
        float e = sS[s] + ldsD[dl];
        e = e > 0.f ? e : SLOPE * e;
        ushort exb = f32_f16(__expf(e));
        atomicAdd(&lden[dl], f16_f32(exb));      // rounded value: consistent w/ numerator
        int slot = atomicAdd(&lcur[dl], 1);
        lsrc[slot] = (ushort)s;
        lex[slot]  = exb;
    }
    __syncthreads();
    if (t < BNODES && node < N_NODES) denom[node] = lden[t];
    for (int i = t; i < n; i += 256)
        srcEx[beg + i] = ((uint)lsrc[i] << 16) | (uint)lex[i];
}

// ---------------------------------------------------------------------------
// K5: one wave per dst node: acc = sum(ex * z_f16[src]); out = elu(acc/denom)
// No score math, no den reduction — pure gather+FMA.
// ---------------------------------------------------------------------------
__global__ __launch_bounds__(256) void k_aggc(const ushort* __restrict__ zh,
                                              const uint* __restrict__ srcEx,
                                              const float* __restrict__ denom,
                                              const int* __restrict__ rowptr,
                                              float* __restrict__ out) {
    int node = blockIdx.x * 4 + (threadIdx.x >> 6);
    int lane = threadIdx.x & 63;
    int beg = rowptr[node], end = rowptr[node + 1];
    float acc = 0.f;
    int k = beg;
    for (; k + 4 <= end; k += 4) {
        uint w0 = srcEx[k],     w1 = srcEx[k + 1];
        uint w2 = srcEx[k + 2], w3 = srcEx[k + 3];
        float v0 = f16_f32((ushort)(w0 & 0xFFFF));
        float v1 = f16_f32((ushort)(w1 & 0xFFFF));
        float v2 = f16_f32((ushort)(w2 & 0xFFFF));
        float v3 = f16_f32((ushort)(w3 & 0xFFFF));
        float z0 = f16_f32(zh[((size_t)(w0 >> 16) << 6) + lane]);
        float z1 = f16_f32(zh[((size_t)(w1 >> 16) << 6) + lane]);
        float z2 = f16_f32(zh[((size_t)(w2 >> 16) << 6) + lane]);
        float z3 = f16_f32(zh[((size_t)(w3 >> 16) << 6) + lane]);
        acc += v0 * z0; acc += v1 * z1; acc += v2 * z2; acc += v3 * z3;
    }
    for (; k < end; ++k) {
        uint w = srcEx[k];
        acc += f16_f32((ushort)(w & 0xFFFF)) *
               f16_f32(zh[((size_t)(w >> 16) << 6) + lane]);
    }
    float den = denom[node];
    float r = den > 0.f ? acc / den : 0.f;
    out[(size_t)node * OUT_DIM + lane] = r > 0.f ? r : expm1f(r);
}

static inline char* alignup(char* p) {
    return (char*)(((uintptr_t)p + 63) & ~(uintptr_t)63);
}

extern "C" void kernel_launch(void* const* d_in, const int* in_sizes, int n_in,
                              void* d_out, int out_size, void* d_ws, size_t ws_size,
                              hipStream_t stream) {
    const float* h     = (const float*)d_in[0];
    const float* Wfc   = (const float*)d_in[1];
    const float* Wattn = (const float*)d_in[2];
    const int*   src   = (const int*)d_in[3];
    const int*   dst   = (const int*)d_in[4];
    float* out = (float*)d_out;

    // workspace layout (64B-aligned regions)
    char* p = (char*)d_ws;
    uint*   binned    = (uint*)p;             p = alignup(p + (size_t)N_EDGES * 4);
    uint*   srcEx     = (uint*)p;             p = alignup(p + (size_t)N_EDGES * 4);
    int*    rowptrF   = (int*)p;              p = alignup(p + (size_t)(N_NODES + 1) * 4);
    float*  sS        = (float*)p;            p = alignup(p + (size_t)N_NODES * 4);
    float*  sD        = (float*)p;            p = alignup(p + (size_t)N_NODES * 4);
    float*  denom     = (float*)p;            p = alignup(p + (size_t)N_NODES * 4);
    int*    gcount    = (int*)p;              p = alignup(p + NBKT * 4);
    int*    bucketPtr = (int*)p;              p = alignup(p + (NBKT + 1) * 4);
    int*    bucketCur = (int*)p;              p = alignup(p + NBKT * 4);
    ushort* Whi       = (ushort*)p;           p = alignup(p + OUT_DIM * IN_DIM * 2);
    ushort* Wlo       = (ushort*)p;           p = alignup(p + OUT_DIM * IN_DIM * 2);
    ushort* zh        = (ushort*)p;

    hipMemsetAsync(gcount, 0, NBKT * sizeof(int), stream);

    k_prep_hist<<<256 + 64, 256, 0, stream>>>(Wfc, Whi, Wlo, dst, gcount);
    k_gemm<<<N_NODES / 16, 64, 0, stream>>>(h, Whi, Wlo, Wattn, zh, sS, sD);
    k_scan<<<1, 256, 0, stream>>>(gcount, bucketPtr, bucketCur);
    k_bin<<<(N_EDGES + EPB - 1) / EPB, 256, 0, stream>>>(src, dst, bucketCur, binned);
    k_sort<<<NBKT, 256, 0, stream>>>(binned, bucketPtr, sS, sD, srcEx, denom, rowptrF);
    k_aggc<<<N_NODES / 4, 256, 0, stream>>>(zh, srcEx, denom, rowptrF, out);
}